// Round 6
// baseline (1670.991 us; speedup 1.0000x reference)
//
#include <hip/hip_runtime.h>
#include <hip/hip_bf16.h>

#define Mm 8
#define Nn 512
#define NEe 409
#define NIi 103
#define Bb 512
#define Dd 243
#define Tt 16
#define SPROW 640      // spike row bytes (i8): e[0:409) pad[409:512) i[512:615) pad[615:640)
#define WCROW 1152     // packed weight row bytes (i8): inter(512) | E-rec(512) | I-rec(128)
#define DEC_I 0.33333334f  // (float)(1.0 - 1.0/1.5)
#define NBLK 512

typedef int v4i __attribute__((ext_vector_type(4)));

__device__ __forceinline__ float quantf(float w) {
    // fake_quant forward == clip(round-half-even(w), -8, 7)  (step = 1.0)
    float q = rintf(w);
    return fminf(fmaxf(q, -8.0f), 7.0f);
}

// ---------------- zero spike buffers + barrier (ws is poisoned each call) -----------
__global__ void k_zero(int4* __restrict__ p, int n) {
    int i = blockIdx.x * blockDim.x + threadIdx.x;
    if (i < n) p[i] = make_int4(0, 0, 0, 0);
}

// ---------------- pack quantized recurrent weights as i8 (exact small ints) ---------
__global__ void k_pack(const float* __restrict__ Wint, const float* __restrict__ WEE,
                       const float* __restrict__ WEI, const float* __restrict__ WIE,
                       const float* __restrict__ WII, signed char* __restrict__ Wc) {
    int i = blockIdx.x * 256 + threadIdx.x;
    if (i >= Mm * Nn * WCROW) return;
    int k = i % WCROW;
    int n = (i / WCROW) & (Nn - 1);
    int m = i / (WCROW * Nn);
    float w = 0.0f;
    if (k < 512) {
        if (k < NEe) w = Wint[((((m + 7) & 7) * Nn) + n) * NEe + k];
    } else if (k < 1024) {
        int j = k - 512;
        if (j < NEe) w = (n < NEe) ? WEE[((m * NEe) + n) * NEe + j]
                                   : WEI[((m * NIi) + (n - NEe)) * NEe + j];
    } else {
        int j = k - 1024;
        if (j < NIi) w = (n < NEe) ? WIE[((m * NEe) + n) * NIi + j]
                                   : WII[((m * NIi) + (n - NEe)) * NIi + j];
    }
    Wc[i] = (signed char)(int)quantf(w);
}

// ---------------- ext_proj = x @ qW_in^T + b_in  (fp32, sequential over d) ----------
__global__ void k_ext(const float* __restrict__ x, const float* __restrict__ Win,
                      const float* __restrict__ bin, float* __restrict__ ext) {
    __shared__ float xs[64][68];
    __shared__ float wsm[64][68];
    const int bid = blockIdx.x;          // 512 blocks: m(8) x bt(8) x nt(8)
    const int m  = bid >> 6;
    const int bt = (bid >> 3) & 7;
    const int nt = bid & 7;
    const int b0 = bt * 64, n0 = nt * 64;
    const int t = threadIdx.x;
    const int tb4 = (t & 15) * 4;
    const int tn4 = (t >> 4) * 4;
    const int sr = t >> 2;
    const int sc = (t & 3) * 16;
    float c[4][4];
#pragma unroll
    for (int i = 0; i < 4; ++i)
#pragma unroll
        for (int j = 0; j < 4; ++j) c[i][j] = 0.0f;

    for (int d0 = 0; d0 < Dd; d0 += 64) {
#pragma unroll
        for (int j = 0; j < 16; ++j) {
            int d = d0 + sc + j;
            float xv = 0.0f, wv = 0.0f;
            if (d < Dd) {
                xv = x[(b0 + sr) * Dd + d];
                wv = quantf(Win[((m * Nn) + n0 + sr) * Dd + d]);
            }
            xs[sc + j][sr] = xv;
            wsm[sc + j][sr] = wv;
        }
        __syncthreads();
        const int dmax = min(64, Dd - d0);
        for (int d = 0; d < dmax; ++d) {
            float4 av = *(const float4*)&xs[d][tb4];
            float4 wv = *(const float4*)&wsm[d][tn4];
            float a[4] = {av.x, av.y, av.z, av.w};
            float wq[4] = {wv.x, wv.y, wv.z, wv.w};
#pragma unroll
            for (int i = 0; i < 4; ++i)
#pragma unroll
                for (int j = 0; j < 4; ++j)
                    c[i][j] = fmaf(a[i], wq[j], c[i][j]);
        }
        __syncthreads();
    }
#pragma unroll
    for (int i = 0; i < 4; ++i)
#pragma unroll
        for (int j = 0; j < 4; ++j) {
            float val = __fadd_rn(c[i][j], bin[m * Nn + n0 + tn4 + j]);
            ext[(size_t)(m * Bb + b0 + tb4 + i) * Nn + n0 + tn4 + j] = val;
        }
}

// ---- manual grid barrier (hipCG grid.sync mechanism; bounded spin as hang insurance)
__device__ __forceinline__ void gbar(int* __restrict__ bar, int tid) {
    __syncthreads();                      // drains this block's stores (vmcnt 0)
    if (tid == 0) {
        __threadfence();                  // agent release: L2 writeback
        int g = __hip_atomic_load(&bar[1], __ATOMIC_ACQUIRE, __HIP_MEMORY_SCOPE_AGENT);
        int old = __hip_atomic_fetch_add(&bar[0], 1, __ATOMIC_ACQ_REL, __HIP_MEMORY_SCOPE_AGENT);
        if (old == NBLK - 1) {
            __hip_atomic_store(&bar[0], 0, __ATOMIC_RELAXED, __HIP_MEMORY_SCOPE_AGENT);
            __hip_atomic_fetch_add(&bar[1], 1, __ATOMIC_ACQ_REL, __HIP_MEMORY_SCOPE_AGENT);
        } else {
            int spin = 0;
            while (__hip_atomic_load(&bar[1], __ATOMIC_ACQUIRE, __HIP_MEMORY_SCOPE_AGENT) == g) {
                __builtin_amdgcn_s_sleep(16);
                if (++spin > 3000000) break;   // bail: wrong answer beats a hang
            }
        }
        __threadfence();                  // agent acquire: L2 invalidate
    }
    __syncthreads();
}

// ---------------- persistent 16-tick LIF: i8 MFMA GEMM, state in registers ----------
// 512 WGs x 256 thr (4 waves); 2 blocks/CU guaranteed (36.9 KB LDS, <=256 VGPR via
// launch_bounds(256,2)) -> all 512 blocks co-resident for the manual grid barrier.
// Inner GEMM identical to the round-5 verified i8 kernel.
__global__ void __launch_bounds__(256, 2)
k_ticks(const signed char* __restrict__ Wc,
        signed char* __restrict__ Sp0,
        signed char* __restrict__ Sp1,
        const float* __restrict__ ext,
        float* __restrict__ out,
        int* __restrict__ bar) {
    __shared__ __align__(16) signed char sA[2][64][144];   // 128 + 16 pad
    __shared__ __align__(16) signed char sB[2][64][144];

    const int wg = blockIdx.x;           // 512: m(8) x bt(8) x nt(8)
    const int m  = wg & 7;               // mesh -> XCD affinity heuristic
    const int bt = (wg >> 3) & 7;
    const int nt = wg >> 6;              // 0..7
    const int b0 = bt * 64;
    const int n0 = nt * 64;
    const int pm = (m + 7) & 7;

    const int tid  = threadIdx.x;
    const int w    = tid >> 6;           // 0..3
    const int lane = tid & 63;
    const int bh   = w & 1;              // 32-row half of b-tile
    const int nh   = w >> 1;             // 32-col half of n-tile
    const int quad = lane >> 4;
    const int li   = lane & 15;

    // staging coords: 2 chunks/thread for each of A and B (16 B each)
    int rowS[2], colS[2];
#pragma unroll
    for (int j = 0; j < 2; ++j) { int ch = tid + j * 256; rowS[j] = ch >> 3; colS[j] = (ch & 7) * 16; }

    float decs[2]; int offs[2]; int nels[2];
#pragma unroll
    for (int tn = 0; tn < 2; ++tn) {
        int n = n0 + nh * 32 + tn * 16 + li;
        nels[tn] = n;
        decs[tn] = (n < NEe) ? 0.5f : DEC_I;
        offs[tn] = (n < NEe) ? n : (n + 103);   // i-region of spike row starts at 512
    }
    const int bbase = b0 + bh * 32;

    const signed char* WcBase = Wc + (size_t)(m * Nn + n0) * WCROW;

    // per-thread persistent state in registers for all 16 ticks
    float extr[2][2][4];
#pragma unroll
    for (int tb = 0; tb < 2; ++tb)
#pragma unroll
        for (int tn = 0; tn < 2; ++tn)
#pragma unroll
            for (int r = 0; r < 4; ++r) {
                int b = bbase + tb * 16 + quad * 4 + r;
                extr[tb][tn][r] = ext[(size_t)(m * Bb + b) * Nn + nels[tn]];
            }
    float vmem[2][2][4];
    int cnt[2][2];
#pragma unroll
    for (int tb = 0; tb < 2; ++tb)
#pragma unroll
        for (int tn = 0; tn < 2; ++tn) {
            cnt[tb][tn] = 0;
#pragma unroll
            for (int r = 0; r < 4; ++r) vmem[tb][tn][r] = 0.0f;
        }

    for (int t = 0; t < Tt; ++t) {
        const signed char* SR = (t & 1) ? Sp1 : Sp0;
        signed char* SW       = (t & 1) ? Sp0 : Sp1;
        const signed char* AbasePrev = SR + (size_t)(pm * Bb + b0) * SPROW;
        const signed char* AbaseOwn  = SR + (size_t)(m  * Bb + b0) * SPROW;

        v4i acc[2][2];
#pragma unroll
        for (int tb = 0; tb < 2; ++tb)
#pragma unroll
            for (int tn = 0; tn < 2; ++tn) acc[tb][tn] = (v4i){0, 0, 0, 0};
        float c[2][2][4];

        // stage chunk 0 (k0=0 -> prev-mesh e segment)
#pragma unroll
        for (int j = 0; j < 2; ++j) {
            *(v4i*)&sA[0][rowS[j]][colS[j]] = *(const v4i*)(AbasePrev + (size_t)rowS[j] * SPROW + colS[j]);
            *(v4i*)&sB[0][rowS[j]][colS[j]] = *(const v4i*)(WcBase + (size_t)rowS[j] * WCROW + colS[j]);
        }
        __syncthreads();

        for (int it = 0; it < 9; ++it) {
            const int buf = it & 1;
            v4i nA[2], nB[2];
            if (it < 8) {
                const int k0 = (it + 1) * 128;
                const signed char* ab; int ko;
                if (k0 < 512) { ab = AbasePrev; ko = k0; }
                else          { ab = AbaseOwn;  ko = k0 - 512; }
#pragma unroll
                for (int j = 0; j < 2; ++j) {
                    nA[j] = *(const v4i*)(ab + (size_t)rowS[j] * SPROW + ko + colS[j]);
                    nB[j] = *(const v4i*)(WcBase + (size_t)rowS[j] * WCROW + k0 + colS[j]);
                }
            }
            // compute current chunk: 2 k-steps of 64
#pragma unroll
            for (int ks = 0; ks < 128; ks += 64) {
                v4i af0 = *(const v4i*)&sA[buf][bh * 32 + li][ks + quad * 16];
                v4i af1 = *(const v4i*)&sA[buf][bh * 32 + 16 + li][ks + quad * 16];
#pragma unroll
                for (int tn = 0; tn < 2; ++tn) {
                    v4i bfr = *(const v4i*)&sB[buf][nh * 32 + tn * 16 + li][ks + quad * 16];
                    acc[0][tn] = __builtin_amdgcn_mfma_i32_16x16x64_i8(af0, bfr, acc[0][tn], 0, 0, 0);
                    acc[1][tn] = __builtin_amdgcn_mfma_i32_16x16x64_i8(af1, bfr, acc[1][tn], 0, 0, 0);
                }
            }
            if (it < 8) {
                const int nb = buf ^ 1;
#pragma unroll
                for (int j = 0; j < 2; ++j) {
                    *(v4i*)&sA[nb][rowS[j]][colS[j]] = nA[j];
                    *(v4i*)&sB[nb][rowS[j]][colS[j]] = nB[j];
                }
            }
            __syncthreads();
            // segment flushes preserve the reference's exact fp32 add order:
            // c = ((ext_proj+inter) + Erec) + Irec; each partial is an exact integer.
            if (it == 3) {
#pragma unroll
                for (int tb = 0; tb < 2; ++tb)
#pragma unroll
                    for (int tn = 0; tn < 2; ++tn) {
#pragma unroll
                        for (int r = 0; r < 4; ++r)
                            c[tb][tn][r] = __fadd_rn(extr[tb][tn][r], (float)acc[tb][tn][r]);
                        acc[tb][tn] = (v4i){0, 0, 0, 0};
                    }
            } else if (it == 7 || it == 8) {
#pragma unroll
                for (int tb = 0; tb < 2; ++tb)
#pragma unroll
                    for (int tn = 0; tn < 2; ++tn) {
#pragma unroll
                        for (int r = 0; r < 4; ++r)
                            c[tb][tn][r] = __fadd_rn(c[tb][tn][r], (float)acc[tb][tn][r]);
                        acc[tb][tn] = (v4i){0, 0, 0, 0};
                    }
            }
        }

        // LIF update, exact np op order: v' = (v*decay) + c; spike iff v' >= 1.0
#pragma unroll
        for (int tb = 0; tb < 2; ++tb)
#pragma unroll
            for (int tn = 0; tn < 2; ++tn)
#pragma unroll
                for (int r = 0; r < 4; ++r) {
                    float vn = __fadd_rn(__fmul_rn(vmem[tb][tn][r], decs[tn]), c[tb][tn][r]);
                    int s = (vn >= 1.0f) ? 1 : 0;
                    vmem[tb][tn][r] = s ? 0.0f : vn;
                    cnt[tb][tn] += s << (r * 8);
                    if (t < Tt - 1) {
                        int b = bbase + tb * 16 + quad * 4 + r;
                        SW[(size_t)(m * Bb + b) * SPROW + offs[tn]] = (signed char)s;
                    }
                }
        if (t < Tt - 1) gbar(bar, tid);
    }

    // out[b][m*N + n] = spike count (single write at the end)
#pragma unroll
    for (int tb = 0; tb < 2; ++tb)
#pragma unroll
        for (int tn = 0; tn < 2; ++tn)
#pragma unroll
            for (int r = 0; r < 4; ++r) {
                int b = bbase + tb * 16 + quad * 4 + r;
                out[(size_t)b * (Mm * Nn) + m * Nn + nels[tn]] =
                    (float)((cnt[tb][tn] >> (r * 8)) & 0xff);
            }
}

extern "C" void kernel_launch(void* const* d_in, const int* in_sizes, int n_in,
                              void* d_out, int out_size, void* d_ws, size_t ws_size,
                              hipStream_t stream) {
    const float* x    = (const float*)d_in[0];
    const float* Win  = (const float*)d_in[1];
    const float* bin  = (const float*)d_in[2];
    const float* Wint = (const float*)d_in[3];
    const float* WEE  = (const float*)d_in[4];
    const float* WEI  = (const float*)d_in[5];
    const float* WIE  = (const float*)d_in[6];
    const float* WII  = (const float*)d_in[7];
    float* out = (float*)d_out;

    char* ws = (char*)d_ws;
    signed char* Wc  = (signed char*)ws;                       // 8*512*1152 = 4,718,592
    signed char* Sp0 = (signed char*)(ws + 4718592);           // 8*512*640  = 2,621,440
    signed char* Sp1 = Sp0 + 2621440;
    int* bar = (int*)(ws + 4718592 + 2 * 2621440);             // 16 B (zeroed every call)
    float* extw = (float*)(ws + 4718592 + 2 * 2621440 + 16);   // 8*512*512*4 = 8,388,608

    // zero Sp0+Sp1+bar in one pass (ws is re-poisoned 0xAA before every call)
    int n16 = (2 * 2621440 + 16) / 16;
    k_zero<<<(n16 + 255) / 256, 256, 0, stream>>>((int4*)Sp0, n16);
    k_pack<<<(Mm * Nn * WCROW + 255) / 256, 256, 0, stream>>>(Wint, WEE, WEI, WIE, WII, Wc);
    k_ext<<<512, 256, 0, stream>>>(x, Win, bin, extw);

    k_ticks<<<NBLK, 256, 0, stream>>>(Wc, Sp0, Sp1, (const float*)extw, out, bar);
}

// Round 7
// 536.797 us; speedup vs baseline: 3.1129x; 3.1129x over previous
//
#include <hip/hip_runtime.h>
#include <hip/hip_bf16.h>

#define Mm 8
#define Nn 512
#define NEe 409
#define NIi 103
#define Bb 512
#define Dd 243
#define Tt 16
#define SPROW 640      // spike row bytes (i8): e[0:409) pad[409:512) i[512:615) pad[615:640)
#define WCROW 1152     // packed weight row bytes (i8): inter(512) | E-rec(512) | I-rec(128)
#define DEC_I 0.33333334f  // (float)(1.0 - 1.0/1.5)
#define NBLK 512
#define FLAGSTRIDE 16  // one flag per 64B cache line

typedef int v4i __attribute__((ext_vector_type(4)));

__device__ __forceinline__ float quantf(float w) {
    // fake_quant forward == clip(round-half-even(w), -8, 7)  (step = 1.0)
    float q = rintf(w);
    return fminf(fmaxf(q, -8.0f), 7.0f);
}

// ---------------- zero spike buffers + flags (ws is poisoned each call) -------------
__global__ void k_zero(int4* __restrict__ p, int n) {
    int i = blockIdx.x * blockDim.x + threadIdx.x;
    if (i < n) p[i] = make_int4(0, 0, 0, 0);
}

// ---------------- pack quantized recurrent weights as i8 (exact small ints) ---------
__global__ void k_pack(const float* __restrict__ Wint, const float* __restrict__ WEE,
                       const float* __restrict__ WEI, const float* __restrict__ WIE,
                       const float* __restrict__ WII, signed char* __restrict__ Wc) {
    int i = blockIdx.x * 256 + threadIdx.x;
    if (i >= Mm * Nn * WCROW) return;
    int k = i % WCROW;
    int n = (i / WCROW) & (Nn - 1);
    int m = i / (WCROW * Nn);
    float w = 0.0f;
    if (k < 512) {
        if (k < NEe) w = Wint[((((m + 7) & 7) * Nn) + n) * NEe + k];
    } else if (k < 1024) {
        int j = k - 512;
        if (j < NEe) w = (n < NEe) ? WEE[((m * NEe) + n) * NEe + j]
                                   : WEI[((m * NIi) + (n - NEe)) * NEe + j];
    } else {
        int j = k - 1024;
        if (j < NIi) w = (n < NEe) ? WIE[((m * NEe) + n) * NIi + j]
                                   : WII[((m * NIi) + (n - NEe)) * NIi + j];
    }
    Wc[i] = (signed char)(int)quantf(w);
}

// ---------------- ext_proj = x @ qW_in^T + b_in  (fp32, sequential over d) ----------
__global__ void k_ext(const float* __restrict__ x, const float* __restrict__ Win,
                      const float* __restrict__ bin, float* __restrict__ ext) {
    __shared__ float xs[64][68];
    __shared__ float wsm[64][68];
    const int bid = blockIdx.x;          // 512 blocks: m(8) x bt(8) x nt(8)
    const int m  = bid >> 6;
    const int bt = (bid >> 3) & 7;
    const int nt = bid & 7;
    const int b0 = bt * 64, n0 = nt * 64;
    const int t = threadIdx.x;
    const int tb4 = (t & 15) * 4;
    const int tn4 = (t >> 4) * 4;
    const int sr = t >> 2;
    const int sc = (t & 3) * 16;
    float c[4][4];
#pragma unroll
    for (int i = 0; i < 4; ++i)
#pragma unroll
        for (int j = 0; j < 4; ++j) c[i][j] = 0.0f;

    for (int d0 = 0; d0 < Dd; d0 += 64) {
#pragma unroll
        for (int j = 0; j < 16; ++j) {
            int d = d0 + sc + j;
            float xv = 0.0f, wv = 0.0f;
            if (d < Dd) {
                xv = x[(b0 + sr) * Dd + d];
                wv = quantf(Win[((m * Nn) + n0 + sr) * Dd + d]);
            }
            xs[sc + j][sr] = xv;
            wsm[sc + j][sr] = wv;
        }
        __syncthreads();
        const int dmax = min(64, Dd - d0);
        for (int d = 0; d < dmax; ++d) {
            float4 av = *(const float4*)&xs[d][tb4];
            float4 wv = *(const float4*)&wsm[d][tn4];
            float a[4] = {av.x, av.y, av.z, av.w};
            float wq[4] = {wv.x, wv.y, wv.z, wv.w};
#pragma unroll
            for (int i = 0; i < 4; ++i)
#pragma unroll
                for (int j = 0; j < 4; ++j)
                    c[i][j] = fmaf(a[i], wq[j], c[i][j]);
        }
        __syncthreads();
    }
#pragma unroll
    for (int i = 0; i < 4; ++i)
#pragma unroll
        for (int j = 0; j < 4; ++j) {
            float val = __fadd_rn(c[i][j], bin[m * Nn + n0 + tn4 + j]);
            ext[(size_t)(m * Bb + b0 + tb4 + i) * Nn + n0 + tn4 + j] = val;
        }
}

// ---- grid barrier v2: store-flag protocol, no serialized RMW, no per-poll invalidate
// arrive: block wg release-stores t+1 to its own cache line (512 parallel stores)
// check:  block 0's 256 threads poll 2 flags each (RELAXED sc1 loads), then set rel
// depart: blocks poll rel RELAXED, then ONE acquire fence (single L1/L2 inv per tick)
__device__ __forceinline__ void gbar(int* __restrict__ flags, int* __restrict__ rel,
                                     int t, int wg, int tid) {
    __syncthreads();                      // all this block's spike stores issued
    if (tid == 0)
        __hip_atomic_store(&flags[wg * FLAGSTRIDE], t + 1,
                           __ATOMIC_RELEASE, __HIP_MEMORY_SCOPE_AGENT);
    if (wg == 0) {
        long spin = 0;
        while (__hip_atomic_load(&flags[tid * FLAGSTRIDE],
                                 __ATOMIC_RELAXED, __HIP_MEMORY_SCOPE_AGENT) < t + 1) {
            __builtin_amdgcn_s_sleep(1);
            if (++spin > 200000000L) break;   // bail: wrong answer beats a hang
        }
        spin = 0;
        while (__hip_atomic_load(&flags[(tid + 256) * FLAGSTRIDE],
                                 __ATOMIC_RELAXED, __HIP_MEMORY_SCOPE_AGENT) < t + 1) {
            __builtin_amdgcn_s_sleep(1);
            if (++spin > 200000000L) break;
        }
        __syncthreads();
        if (tid == 0)
            __hip_atomic_store(rel, t + 1, __ATOMIC_RELEASE, __HIP_MEMORY_SCOPE_AGENT);
    }
    if (tid == 0) {
        long spin = 0;
        while (__hip_atomic_load(rel, __ATOMIC_RELAXED, __HIP_MEMORY_SCOPE_AGENT) < t + 1) {
            __builtin_amdgcn_s_sleep(1);
            if (++spin > 200000000L) break;
        }
        __builtin_amdgcn_fence(__ATOMIC_ACQUIRE, "agent");   // one inv per tick
    }
    __syncthreads();
}

// ---------------- persistent 16-tick LIF: i8 MFMA GEMM, state in registers ----------
// 512 WGs x 256 thr (4 waves); 2 blocks/CU (36.9 KB LDS, 112 VGPR) -> all co-resident
// (proven by round 6's correct result). Inner GEMM identical to round-5 verified code.
__global__ void __launch_bounds__(256, 2)
k_ticks(const signed char* __restrict__ Wc,
        signed char* __restrict__ Sp0,
        signed char* __restrict__ Sp1,
        const float* __restrict__ ext,
        float* __restrict__ out,
        int* __restrict__ flags,
        int* __restrict__ rel) {
    __shared__ __align__(16) signed char sA[2][64][144];   // 128 + 16 pad
    __shared__ __align__(16) signed char sB[2][64][144];

    const int wg = blockIdx.x;           // 512: m(8) x bt(8) x nt(8)
    const int m  = wg & 7;               // mesh -> XCD affinity heuristic
    const int bt = (wg >> 3) & 7;
    const int nt = wg >> 6;              // 0..7
    const int b0 = bt * 64;
    const int n0 = nt * 64;
    const int pm = (m + 7) & 7;

    const int tid  = threadIdx.x;
    const int w    = tid >> 6;           // 0..3
    const int lane = tid & 63;
    const int bh   = w & 1;              // 32-row half of b-tile
    const int nh   = w >> 1;             // 32-col half of n-tile
    const int quad = lane >> 4;
    const int li   = lane & 15;

    // staging coords: 2 chunks/thread for each of A and B (16 B each)
    int rowS[2], colS[2];
#pragma unroll
    for (int j = 0; j < 2; ++j) { int ch = tid + j * 256; rowS[j] = ch >> 3; colS[j] = (ch & 7) * 16; }

    float decs[2]; int offs[2]; int nels[2];
#pragma unroll
    for (int tn = 0; tn < 2; ++tn) {
        int n = n0 + nh * 32 + tn * 16 + li;
        nels[tn] = n;
        decs[tn] = (n < NEe) ? 0.5f : DEC_I;
        offs[tn] = (n < NEe) ? n : (n + 103);   // i-region of spike row starts at 512
    }
    const int bbase = b0 + bh * 32;

    const signed char* WcBase = Wc + (size_t)(m * Nn + n0) * WCROW;

    // per-thread persistent state in registers for all 16 ticks
    float extr[2][2][4];
#pragma unroll
    for (int tb = 0; tb < 2; ++tb)
#pragma unroll
        for (int tn = 0; tn < 2; ++tn)
#pragma unroll
            for (int r = 0; r < 4; ++r) {
                int b = bbase + tb * 16 + quad * 4 + r;
                extr[tb][tn][r] = ext[(size_t)(m * Bb + b) * Nn + nels[tn]];
            }
    float vmem[2][2][4];
    int cnt[2][2];
#pragma unroll
    for (int tb = 0; tb < 2; ++tb)
#pragma unroll
        for (int tn = 0; tn < 2; ++tn) {
            cnt[tb][tn] = 0;
#pragma unroll
            for (int r = 0; r < 4; ++r) vmem[tb][tn][r] = 0.0f;
        }

    for (int t = 0; t < Tt; ++t) {
        const signed char* SR = (t & 1) ? Sp1 : Sp0;
        signed char* SW       = (t & 1) ? Sp0 : Sp1;
        const signed char* AbasePrev = SR + (size_t)(pm * Bb + b0) * SPROW;
        const signed char* AbaseOwn  = SR + (size_t)(m  * Bb + b0) * SPROW;

        v4i acc[2][2];
#pragma unroll
        for (int tb = 0; tb < 2; ++tb)
#pragma unroll
            for (int tn = 0; tn < 2; ++tn) acc[tb][tn] = (v4i){0, 0, 0, 0};
        float c[2][2][4];

        // stage chunk 0 (k0=0 -> prev-mesh e segment)
#pragma unroll
        for (int j = 0; j < 2; ++j) {
            *(v4i*)&sA[0][rowS[j]][colS[j]] = *(const v4i*)(AbasePrev + (size_t)rowS[j] * SPROW + colS[j]);
            *(v4i*)&sB[0][rowS[j]][colS[j]] = *(const v4i*)(WcBase + (size_t)rowS[j] * WCROW + colS[j]);
        }
        __syncthreads();

        for (int it = 0; it < 9; ++it) {
            const int buf = it & 1;
            v4i nA[2], nB[2];
            if (it < 8) {
                const int k0 = (it + 1) * 128;
                const signed char* ab; int ko;
                if (k0 < 512) { ab = AbasePrev; ko = k0; }
                else          { ab = AbaseOwn;  ko = k0 - 512; }
#pragma unroll
                for (int j = 0; j < 2; ++j) {
                    nA[j] = *(const v4i*)(ab + (size_t)rowS[j] * SPROW + ko + colS[j]);
                    nB[j] = *(const v4i*)(WcBase + (size_t)rowS[j] * WCROW + k0 + colS[j]);
                }
            }
            // compute current chunk: 2 k-steps of 64
#pragma unroll
            for (int ks = 0; ks < 128; ks += 64) {
                v4i af0 = *(const v4i*)&sA[buf][bh * 32 + li][ks + quad * 16];
                v4i af1 = *(const v4i*)&sA[buf][bh * 32 + 16 + li][ks + quad * 16];
#pragma unroll
                for (int tn = 0; tn < 2; ++tn) {
                    v4i bfr = *(const v4i*)&sB[buf][nh * 32 + tn * 16 + li][ks + quad * 16];
                    acc[0][tn] = __builtin_amdgcn_mfma_i32_16x16x64_i8(af0, bfr, acc[0][tn], 0, 0, 0);
                    acc[1][tn] = __builtin_amdgcn_mfma_i32_16x16x64_i8(af1, bfr, acc[1][tn], 0, 0, 0);
                }
            }
            if (it < 8) {
                const int nb = buf ^ 1;
#pragma unroll
                for (int j = 0; j < 2; ++j) {
                    *(v4i*)&sA[nb][rowS[j]][colS[j]] = nA[j];
                    *(v4i*)&sB[nb][rowS[j]][colS[j]] = nB[j];
                }
            }
            __syncthreads();
            // segment flushes preserve the reference's exact fp32 add order:
            // c = ((ext_proj+inter) + Erec) + Irec; each partial is an exact integer.
            if (it == 3) {
#pragma unroll
                for (int tb = 0; tb < 2; ++tb)
#pragma unroll
                    for (int tn = 0; tn < 2; ++tn) {
#pragma unroll
                        for (int r = 0; r < 4; ++r)
                            c[tb][tn][r] = __fadd_rn(extr[tb][tn][r], (float)acc[tb][tn][r]);
                        acc[tb][tn] = (v4i){0, 0, 0, 0};
                    }
            } else if (it == 7 || it == 8) {
#pragma unroll
                for (int tb = 0; tb < 2; ++tb)
#pragma unroll
                    for (int tn = 0; tn < 2; ++tn) {
#pragma unroll
                        for (int r = 0; r < 4; ++r)
                            c[tb][tn][r] = __fadd_rn(c[tb][tn][r], (float)acc[tb][tn][r]);
                        acc[tb][tn] = (v4i){0, 0, 0, 0};
                    }
            }
        }

        // LIF update, exact np op order: v' = (v*decay) + c; spike iff v' >= 1.0
#pragma unroll
        for (int tb = 0; tb < 2; ++tb)
#pragma unroll
            for (int tn = 0; tn < 2; ++tn)
#pragma unroll
                for (int r = 0; r < 4; ++r) {
                    float vn = __fadd_rn(__fmul_rn(vmem[tb][tn][r], decs[tn]), c[tb][tn][r]);
                    int s = (vn >= 1.0f) ? 1 : 0;
                    vmem[tb][tn][r] = s ? 0.0f : vn;
                    cnt[tb][tn] += s << (r * 8);
                    if (t < Tt - 1) {
                        int b = bbase + tb * 16 + quad * 4 + r;
                        SW[(size_t)(m * Bb + b) * SPROW + offs[tn]] = (signed char)s;
                    }
                }
        if (t < Tt - 1) gbar(flags, rel, t, wg, tid);
    }

    // out[b][m*N + n] = spike count (single write at the end)
#pragma unroll
    for (int tb = 0; tb < 2; ++tb)
#pragma unroll
        for (int tn = 0; tn < 2; ++tn)
#pragma unroll
            for (int r = 0; r < 4; ++r) {
                int b = bbase + tb * 16 + quad * 4 + r;
                out[(size_t)b * (Mm * Nn) + m * Nn + nels[tn]] =
                    (float)((cnt[tb][tn] >> (r * 8)) & 0xff);
            }
}

extern "C" void kernel_launch(void* const* d_in, const int* in_sizes, int n_in,
                              void* d_out, int out_size, void* d_ws, size_t ws_size,
                              hipStream_t stream) {
    const float* x    = (const float*)d_in[0];
    const float* Win  = (const float*)d_in[1];
    const float* bin  = (const float*)d_in[2];
    const float* Wint = (const float*)d_in[3];
    const float* WEE  = (const float*)d_in[4];
    const float* WEI  = (const float*)d_in[5];
    const float* WIE  = (const float*)d_in[6];
    const float* WII  = (const float*)d_in[7];
    float* out = (float*)d_out;

    char* ws = (char*)d_ws;
    signed char* Wc  = (signed char*)ws;                       // 8*512*1152 = 4,718,592
    signed char* Sp0 = (signed char*)(ws + 4718592);           // 8*512*640  = 2,621,440
    signed char* Sp1 = Sp0 + 2621440;
    int* flags = (int*)(ws + 4718592 + 2 * 2621440);           // 512 * 64 B = 32,768
    int* rel   = (int*)(ws + 4718592 + 2 * 2621440 + 32768);   // 64 B
    float* extw = (float*)(ws + 4718592 + 2 * 2621440 + 32768 + 64);  // 8,388,608

    // zero Sp0+Sp1+flags+rel in one pass (ws is re-poisoned 0xAA before every call)
    int n16 = (2 * 2621440 + 32768 + 64) / 16;
    k_zero<<<(n16 + 255) / 256, 256, 0, stream>>>((int4*)Sp0, n16);
    k_pack<<<(Mm * Nn * WCROW + 255) / 256, 256, 0, stream>>>(Wint, WEE, WEI, WIE, WII, Wc);
    k_ext<<<512, 256, 0, stream>>>(x, Win, bin, extw);

    k_ticks<<<NBLK, 256, 0, stream>>>(Wc, Sp0, Sp1, (const float*)extw, out, flags, rel);
}

// Round 8
// 244.067 us; speedup vs baseline: 6.8464x; 2.1994x over previous
//
#include <hip/hip_runtime.h>
#include <hip/hip_bf16.h>

#define Mm 8
#define Nn 512
#define NEe 409
#define NIi 103
#define Bb 512
#define Dd 243
#define Tt 16
#define SPROW 640      // spike row bytes (i8): e[0:409) pad[409:512) i[512:615) pad[615:640)
#define WCROW 1152     // packed weight row bytes (i8): inter(512) | E-rec(512) | I-rec(128)
#define DEC_I 0.33333334f  // (float)(1.0 - 1.0/1.5)
#define NBLK 512
#define FLAGSTRIDE 16  // one flag per 64B cache line
#define SPINMAX 1000000L

typedef int v4i __attribute__((ext_vector_type(4)));
union LV { long l[2]; v4i v; };

__device__ __forceinline__ float quantf(float w) {
    // fake_quant forward == clip(round-half-even(w), -8, 7)  (step = 1.0)
    float q = rintf(w);
    return fminf(fmaxf(q, -8.0f), 7.0f);
}

// ---- zero spike buffers + flags via agent atomics (zeros must live at L3, since
// ---- k_ticks reads spikes with L2-bypassing atomic loads)
__global__ void k_zero(int* __restrict__ p, int n) {
    int i = blockIdx.x * blockDim.x + threadIdx.x;
    if (i < n) __hip_atomic_store(&p[i], 0, __ATOMIC_RELAXED, __HIP_MEMORY_SCOPE_AGENT);
}

// ---------------- pack quantized recurrent weights as i8 (exact small ints) ---------
__global__ void k_pack(const float* __restrict__ Wint, const float* __restrict__ WEE,
                       const float* __restrict__ WEI, const float* __restrict__ WIE,
                       const float* __restrict__ WII, signed char* __restrict__ Wc) {
    int i = blockIdx.x * 256 + threadIdx.x;
    if (i >= Mm * Nn * WCROW) return;
    int k = i % WCROW;
    int n = (i / WCROW) & (Nn - 1);
    int m = i / (WCROW * Nn);
    float w = 0.0f;
    if (k < 512) {
        if (k < NEe) w = Wint[((((m + 7) & 7) * Nn) + n) * NEe + k];
    } else if (k < 1024) {
        int j = k - 512;
        if (j < NEe) w = (n < NEe) ? WEE[((m * NEe) + n) * NEe + j]
                                   : WEI[((m * NIi) + (n - NEe)) * NEe + j];
    } else {
        int j = k - 1024;
        if (j < NIi) w = (n < NEe) ? WIE[((m * NEe) + n) * NIi + j]
                                   : WII[((m * NIi) + (n - NEe)) * NIi + j];
    }
    Wc[i] = (signed char)(int)quantf(w);
}

// ---------------- ext_proj = x @ qW_in^T + b_in  (fp32, sequential over d) ----------
__global__ void k_ext(const float* __restrict__ x, const float* __restrict__ Win,
                      const float* __restrict__ bin, float* __restrict__ ext) {
    __shared__ float xs[64][68];
    __shared__ float wsm[64][68];
    const int bid = blockIdx.x;          // 512 blocks: m(8) x bt(8) x nt(8)
    const int m  = bid >> 6;
    const int bt = (bid >> 3) & 7;
    const int nt = bid & 7;
    const int b0 = bt * 64, n0 = nt * 64;
    const int t = threadIdx.x;
    const int tb4 = (t & 15) * 4;
    const int tn4 = (t >> 4) * 4;
    const int sr = t >> 2;
    const int sc = (t & 3) * 16;
    float c[4][4];
#pragma unroll
    for (int i = 0; i < 4; ++i)
#pragma unroll
        for (int j = 0; j < 4; ++j) c[i][j] = 0.0f;

    for (int d0 = 0; d0 < Dd; d0 += 64) {
#pragma unroll
        for (int j = 0; j < 16; ++j) {
            int d = d0 + sc + j;
            float xv = 0.0f, wv = 0.0f;
            if (d < Dd) {
                xv = x[(b0 + sr) * Dd + d];
                wv = quantf(Win[((m * Nn) + n0 + sr) * Dd + d]);
            }
            xs[sc + j][sr] = xv;
            wsm[sc + j][sr] = wv;
        }
        __syncthreads();
        const int dmax = min(64, Dd - d0);
        for (int d = 0; d < dmax; ++d) {
            float4 av = *(const float4*)&xs[d][tb4];
            float4 wv = *(const float4*)&wsm[d][tn4];
            float a[4] = {av.x, av.y, av.z, av.w};
            float wq[4] = {wv.x, wv.y, wv.z, wv.w};
#pragma unroll
            for (int i = 0; i < 4; ++i)
#pragma unroll
                for (int j = 0; j < 4; ++j)
                    c[i][j] = fmaf(a[i], wq[j], c[i][j]);
        }
        __syncthreads();
    }
#pragma unroll
    for (int i = 0; i < 4; ++i)
#pragma unroll
        for (int j = 0; j < 4; ++j) {
            float val = __fadd_rn(c[i][j], bin[m * Nn + n0 + tn4 + j]);
            ext[(size_t)(m * Bb + b0 + tb4 + i) * Nn + n0 + tn4 + j] = val;
        }
}

// ---- grid barrier v3: pure relaxed-atomic flag protocol. NO release/acquire fences:
// all cross-tick data (spikes) moves via agent atomics (write-through / L2-bypass),
// so no wbl2/inv cache maintenance is needed anywhere. Monotone counters, no reset.
__device__ __forceinline__ void gbar(int* __restrict__ flags, int* __restrict__ rel,
                                     int t, int wg, int tid) {
    __syncthreads();                      // vmcnt(0): this block's spike atomics acked
    if (tid == 0)
        __hip_atomic_store(&flags[wg * FLAGSTRIDE], t + 1,
                           __ATOMIC_RELAXED, __HIP_MEMORY_SCOPE_AGENT);
    if (wg == 0) {
        long spin = 0;
        while (__hip_atomic_load(&flags[tid * FLAGSTRIDE],
                                 __ATOMIC_RELAXED, __HIP_MEMORY_SCOPE_AGENT) < t + 1) {
            __builtin_amdgcn_s_sleep(2);
            if (++spin > SPINMAX) break;   // bail: wrong answer beats a hang
        }
        spin = 0;
        while (__hip_atomic_load(&flags[(tid + 256) * FLAGSTRIDE],
                                 __ATOMIC_RELAXED, __HIP_MEMORY_SCOPE_AGENT) < t + 1) {
            __builtin_amdgcn_s_sleep(2);
            if (++spin > SPINMAX) break;
        }
        __syncthreads();
        if (tid == 0)
            __hip_atomic_store(rel, t + 1, __ATOMIC_RELAXED, __HIP_MEMORY_SCOPE_AGENT);
    } else if (tid == 0) {
        long spin = 0;
        while (__hip_atomic_load(rel, __ATOMIC_RELAXED, __HIP_MEMORY_SCOPE_AGENT) < t + 1) {
            __builtin_amdgcn_s_sleep(8);
            if (++spin > SPINMAX) break;
        }
    }
    __syncthreads();
}

// ---------------- persistent 16-tick LIF: i8 MFMA GEMM, state in registers ----------
// 512 WGs x 256 thr, 2 blocks/CU co-resident (proven r6/r7). Spikes cross ticks via
// agent atomics; weights/ext stay L2-warm (no invalidates). LDS XOR-swizzled
// (stride 128, chunk ^= row&7) -> conflict-free staging and fragment reads.
__global__ void __launch_bounds__(256, 2)
k_ticks(const signed char* __restrict__ Wc,
        signed char* __restrict__ Sp0,
        signed char* __restrict__ Sp1,
        const float* __restrict__ ext,
        float* __restrict__ out,
        int* __restrict__ flags,
        int* __restrict__ rel) {
    __shared__ __align__(16) signed char sA[2][64][128];
    __shared__ __align__(16) signed char sB[2][64][128];

    const int wg = blockIdx.x;           // 512: m(8) x bt(8) x nt(8)
    const int m  = wg & 7;               // mesh -> XCD affinity heuristic
    const int bt = (wg >> 3) & 7;
    const int nt = wg >> 6;              // 0..7
    const int b0 = bt * 64;
    const int n0 = nt * 64;
    const int pm = (m + 7) & 7;

    const int tid  = threadIdx.x;
    const int w    = tid >> 6;           // 0..3
    const int lane = tid & 63;
    const int bh   = w & 1;              // 32-row half of b-tile
    const int nh   = w >> 1;             // 32-col half of n-tile
    const int quad = lane >> 4;
    const int li   = lane & 15;
    const int lx   = li & 7;             // read-side swizzle key

    // staging coords: 2 chunks/thread each for A and B; col swizzled by row&7
    int rowS[2], gcolS[2], scolS[2];
#pragma unroll
    for (int j = 0; j < 2; ++j) {
        int ch = tid + j * 256;
        rowS[j]  = ch >> 3;
        int cnk  = ch & 7;
        gcolS[j] = cnk * 16;
        scolS[j] = (cnk ^ (rowS[j] & 7)) * 16;
    }

    float decs[2]; int offs[2]; int nels[2];
#pragma unroll
    for (int tn = 0; tn < 2; ++tn) {
        int n = n0 + nh * 32 + tn * 16 + li;
        nels[tn] = n;
        decs[tn] = (n < NEe) ? 0.5f : DEC_I;
        offs[tn] = (n < NEe) ? n : (n + 103);   // i-region of spike row starts at 512
    }
    const int bbase = b0 + bh * 32;

    const signed char* WcBase = Wc + (size_t)(m * Nn + n0) * WCROW;

    // per-thread persistent state in registers for all 16 ticks
    float extr[2][2][4];
#pragma unroll
    for (int tb = 0; tb < 2; ++tb)
#pragma unroll
        for (int tn = 0; tn < 2; ++tn)
#pragma unroll
            for (int r = 0; r < 4; ++r) {
                int b = bbase + tb * 16 + quad * 4 + r;
                extr[tb][tn][r] = ext[(size_t)(m * Bb + b) * Nn + nels[tn]];
            }
    float vmem[2][2][4];
    int cnt[2][2];
#pragma unroll
    for (int tb = 0; tb < 2; ++tb)
#pragma unroll
        for (int tn = 0; tn < 2; ++tn) {
            cnt[tb][tn] = 0;
#pragma unroll
            for (int r = 0; r < 4; ++r) vmem[tb][tn][r] = 0.0f;
        }

    for (int t = 0; t < Tt; ++t) {
        signed char* SR = (t & 1) ? Sp1 : Sp0;
        signed char* SW = (t & 1) ? Sp0 : Sp1;
        signed char* AbasePrev = SR + (size_t)(pm * Bb + b0) * SPROW;
        signed char* AbaseOwn  = SR + (size_t)(m  * Bb + b0) * SPROW;

        v4i acc[2][2];
#pragma unroll
        for (int tb = 0; tb < 2; ++tb)
#pragma unroll
            for (int tn = 0; tn < 2; ++tn) acc[tb][tn] = (v4i){0, 0, 0, 0};
        float c[2][2][4];

        // stage chunk 0 (k0=0 -> prev-mesh e segment); A via agent atomics (L3)
#pragma unroll
        for (int j = 0; j < 2; ++j) {
            long* ap = (long*)(AbasePrev + (size_t)rowS[j] * SPROW + gcolS[j]);
            LV tmp;
            tmp.l[0] = __hip_atomic_load(ap,     __ATOMIC_RELAXED, __HIP_MEMORY_SCOPE_AGENT);
            tmp.l[1] = __hip_atomic_load(ap + 1, __ATOMIC_RELAXED, __HIP_MEMORY_SCOPE_AGENT);
            *(v4i*)&sA[0][rowS[j]][scolS[j]] = tmp.v;
            *(v4i*)&sB[0][rowS[j]][scolS[j]] =
                *(const v4i*)(WcBase + (size_t)rowS[j] * WCROW + gcolS[j]);
        }
        __syncthreads();

        for (int it = 0; it < 9; ++it) {
            const int buf = it & 1;
            v4i nA[2], nB[2];
            if (it < 8) {
                const int k0 = (it + 1) * 128;
                signed char* ab; int ko;
                if (k0 < 512) { ab = AbasePrev; ko = k0; }
                else          { ab = AbaseOwn;  ko = k0 - 512; }
#pragma unroll
                for (int j = 0; j < 2; ++j) {
                    long* ap = (long*)(ab + (size_t)rowS[j] * SPROW + ko + gcolS[j]);
                    LV tmp;
                    tmp.l[0] = __hip_atomic_load(ap,     __ATOMIC_RELAXED, __HIP_MEMORY_SCOPE_AGENT);
                    tmp.l[1] = __hip_atomic_load(ap + 1, __ATOMIC_RELAXED, __HIP_MEMORY_SCOPE_AGENT);
                    nA[j] = tmp.v;
                    nB[j] = *(const v4i*)(WcBase + (size_t)rowS[j] * WCROW + k0 + gcolS[j]);
                }
            }
            // compute current chunk: 2 k-steps of 64 (swizzled fragment reads)
#pragma unroll
            for (int ks = 0; ks < 128; ks += 64) {
                const int c0 = (((ks >> 4) + quad) ^ lx) * 16;
                v4i af0 = *(const v4i*)&sA[buf][bh * 32 + li][c0];
                v4i af1 = *(const v4i*)&sA[buf][bh * 32 + 16 + li][c0];
#pragma unroll
                for (int tn = 0; tn < 2; ++tn) {
                    v4i bfr = *(const v4i*)&sB[buf][nh * 32 + tn * 16 + li][c0];
                    acc[0][tn] = __builtin_amdgcn_mfma_i32_16x16x64_i8(af0, bfr, acc[0][tn], 0, 0, 0);
                    acc[1][tn] = __builtin_amdgcn_mfma_i32_16x16x64_i8(af1, bfr, acc[1][tn], 0, 0, 0);
                }
            }
            if (it < 8) {
                const int nb = buf ^ 1;
#pragma unroll
                for (int j = 0; j < 2; ++j) {
                    *(v4i*)&sA[nb][rowS[j]][scolS[j]] = nA[j];
                    *(v4i*)&sB[nb][rowS[j]][scolS[j]] = nB[j];
                }
            }
            __syncthreads();
            // segment flushes preserve the reference's exact fp32 add order:
            // c = ((ext_proj+inter) + Erec) + Irec; each partial is an exact integer.
            if (it == 3) {
#pragma unroll
                for (int tb = 0; tb < 2; ++tb)
#pragma unroll
                    for (int tn = 0; tn < 2; ++tn) {
#pragma unroll
                        for (int r = 0; r < 4; ++r)
                            c[tb][tn][r] = __fadd_rn(extr[tb][tn][r], (float)acc[tb][tn][r]);
                        acc[tb][tn] = (v4i){0, 0, 0, 0};
                    }
            } else if (it == 7 || it == 8) {
#pragma unroll
                for (int tb = 0; tb < 2; ++tb)
#pragma unroll
                    for (int tn = 0; tn < 2; ++tn) {
#pragma unroll
                        for (int r = 0; r < 4; ++r)
                            c[tb][tn][r] = __fadd_rn(c[tb][tn][r], (float)acc[tb][tn][r]);
                        acc[tb][tn] = (v4i){0, 0, 0, 0};
                    }
            }
        }

        // LIF update, exact np op order: v' = (v*decay) + c; spike iff v' >= 1.0
        // spikes published via agent-scope atomic byte stores (write-through)
#pragma unroll
        for (int tb = 0; tb < 2; ++tb)
#pragma unroll
            for (int tn = 0; tn < 2; ++tn)
#pragma unroll
                for (int r = 0; r < 4; ++r) {
                    float vn = __fadd_rn(__fmul_rn(vmem[tb][tn][r], decs[tn]), c[tb][tn][r]);
                    int s = (vn >= 1.0f) ? 1 : 0;
                    vmem[tb][tn][r] = s ? 0.0f : vn;
                    cnt[tb][tn] += s << (r * 8);
                    if (t < Tt - 1) {
                        int b = bbase + tb * 16 + quad * 4 + r;
                        signed char* sp = SW + (size_t)(m * Bb + b) * SPROW + offs[tn];
                        __hip_atomic_store(sp, (signed char)s,
                                           __ATOMIC_RELAXED, __HIP_MEMORY_SCOPE_AGENT);
                    }
                }
        if (t < Tt - 1) gbar(flags, rel, t, wg, tid);
    }

    // out[b][m*N + n] = spike count (single write at the end)
#pragma unroll
    for (int tb = 0; tb < 2; ++tb)
#pragma unroll
        for (int tn = 0; tn < 2; ++tn)
#pragma unroll
            for (int r = 0; r < 4; ++r) {
                int b = bbase + tb * 16 + quad * 4 + r;
                out[(size_t)b * (Mm * Nn) + m * Nn + nels[tn]] =
                    (float)((cnt[tb][tn] >> (r * 8)) & 0xff);
            }
}

extern "C" void kernel_launch(void* const* d_in, const int* in_sizes, int n_in,
                              void* d_out, int out_size, void* d_ws, size_t ws_size,
                              hipStream_t stream) {
    const float* x    = (const float*)d_in[0];
    const float* Win  = (const float*)d_in[1];
    const float* bin  = (const float*)d_in[2];
    const float* Wint = (const float*)d_in[3];
    const float* WEE  = (const float*)d_in[4];
    const float* WEI  = (const float*)d_in[5];
    const float* WIE  = (const float*)d_in[6];
    const float* WII  = (const float*)d_in[7];
    float* out = (float*)d_out;

    char* ws = (char*)d_ws;
    signed char* Wc  = (signed char*)ws;                       // 8*512*1152 = 4,718,592
    signed char* Sp0 = (signed char*)(ws + 4718592);           // 8*512*640  = 2,621,440
    signed char* Sp1 = Sp0 + 2621440;
    int* flags = (int*)(ws + 4718592 + 2 * 2621440);           // 512 * 64 B = 32,768
    int* rel   = (int*)(ws + 4718592 + 2 * 2621440 + 32768);   // 64 B
    float* extw = (float*)(ws + 4718592 + 2 * 2621440 + 32768 + 64);  // 8,388,608

    // zero Sp0+Sp1+flags+rel via agent atomics (zeros must be visible at L3)
    int nz = (2 * 2621440 + 32768 + 64) / 4;
    k_zero<<<(nz + 255) / 256, 256, 0, stream>>>((int*)Sp0, nz);
    k_pack<<<(Mm * Nn * WCROW + 255) / 256, 256, 0, stream>>>(Wint, WEE, WEI, WIE, WII, Wc);
    k_ext<<<512, 256, 0, stream>>>(x, Win, bin, extw);

    k_ticks<<<NBLK, 256, 0, stream>>>(Wc, Sp0, Sp1, (const float*)extw, out, flags, rel);
}